// Round 7
// baseline (298.348 us; speedup 1.0000x reference)
//
#include <hip/hip_runtime.h>
#include <hip/hip_bf16.h>

#define NVEC   262144
#define NLIST  1024
#define DIM    64
#define NCHUNK 64          // 64 chunks x 16 centroids
#define NGRP   32          // 2 chunks per barrier group
#define SCALE  4096.0f     // score quantum = 1/4096 (= acc ulp at 2^23)
#define MAGIC  10485760.0f // 2^23 + 2^21: pins acc exponent -> bits are monotone
#define DELTA_INT 48       // gap threshold in quanta >= 2x worst flag bound (~23q)

typedef __attribute__((ext_vector_type(8))) short bf16x8;
typedef __attribute__((ext_vector_type(4))) float f32x4;

__device__ __forceinline__ unsigned short bf_rne(float f) {
    unsigned int u = __float_as_uint(f);
    u += 0x7fffu + ((u >> 16) & 1u);
    return (unsigned short)(u >> 16);
}
__device__ __forceinline__ float bf_up(unsigned short s) {
    return __uint_as_float(((unsigned int)s) << 16);
}

// ---------------------------------------------------------------------------
// K0: csq (exact, for fused rescue) + csq4k = SCALE*csq + MAGIC (C-init),
// build cmat in FRAG ORDER with -2*SCALE = -8192 folded in:
//   w = -8192*c;  hi = bf_rne(w);  lo = bf_rne(w - hi)
// chunk ch = 4KB image [frag r 0..3][lane l][8 shorts]:
//   r=0: hi k 0..31   r=1: hi k 32..63   r=2: lo k 0..31   r=3: lo k 32..63
// assign's ds_read_b128 for frag r: lane l reads ch*4096+r*1024+l*16 —
// 64 lanes read a contiguous 1KB; staging order == global_load_lds order.
// ---------------------------------------------------------------------------
__global__ __launch_bounds__(256) void prep_kernel(const float* __restrict__ cents,
                                                   float* __restrict__ csq,
                                                   float* __restrict__ csq4k,
                                                   unsigned short* __restrict__ cmat) {
    int gid = blockIdx.x * 256 + threadIdx.x;     // 0..16383
    if (gid < NLIST) {
        const float4* p = (const float4*)(cents + (size_t)gid * DIM);
        float s = 0.f;
#pragma unroll
        for (int i = 0; i < DIM / 4; ++i) {
            float4 t = p[i];
            s += t.x * t.x + t.y * t.y + t.z * t.z + t.w * t.w;
        }
        csq[gid] = s;
        csq4k[gid] = fmaf(s, SCALE, MAGIC);
    }
    int c   = gid >> 4;        // centroid 0..1023
    int sub = gid & 15;        // r*4 + q
    int r   = sub >> 2;
    int qq  = sub & 3;
    const float* src = cents + (size_t)c * DIM + (r & 1) * 32 + qq * 8;
    unsigned short* dst = cmat + (c >> 4) * 2048 + r * 512 + (qq * 16 + (c & 15)) * 8;
    bool hi = (r < 2);
#pragma unroll
    for (int i = 0; i < 8; ++i) {
        float v = src[i] * -8192.0f;               // fold -2*SCALE, exact pow2
        unsigned short h = bf_rne(v);
        dst[i] = hi ? h : bf_rne(v - bf_up(h));
    }
}

// ---------------------------------------------------------------------------
// K1: MFMA assign + fused gather + FUSED exact rescue (2-kernel pipeline).
// Round-4 skeleton: LDS dbuf staging, grid 2048, 4 waves x 2 tiles/wave,
// (256,6) -> 6 blocks/CU.
// LESSONS (journal): r3/r5 — (256,8) forces VGPR<=32 -> spills, never again.
// r6 — inline asm (v_med3_u32) in the K-loop acts as a scheduling barrier,
// collapsing cross-chunk pipelining (uniform 1.9x wall stretch, busy counts
// unchanged). Epilogue must stay plain C min/max ops.
// Numerics:
//   cmat = -8192*c split hi/lo (bf16 3-term); x split hi/lo (unscaled)
//   acc init = SCALE*csq + MAGIC; acc += w_hi.x_hi + w_lo.x_hi + w_hi.x_lo
//   final acc in [2^23, 2^24): exponent + mantissa bit22 constant -> raw
//   float bits are a monotone unsigned encoding of the quantized score.
// Epilogue per score (4 VALU): e = (bits<<10)+idx; top-2 via min/max/min.
// Flags (gap < DELTA quanta) are BLOCK-LOCAL -> collected in LDS; after the
// gather each wave exact-fp32-rescues one flagged row (same fmaf chain +
// lexicographic argmin as the old rescue kernel) and overwrites the row.
// ---------------------------------------------------------------------------
__global__ __launch_bounds__(256, 6) void assign_mfma(const float* __restrict__ vecs,
                                                      const float* __restrict__ cents,
                                                      const unsigned short* __restrict__ cmat,
                                                      const float* __restrict__ csq4k,
                                                      const float* __restrict__ csq,
                                                      float* __restrict__ out) {
    __shared__ __align__(16) unsigned short chunkbuf[2][2 * 2048];  // 16 KB
    __shared__ unsigned short widx[128];                            // 256 B
    __shared__ unsigned short flg[128];
    __shared__ int flg_n;

    const int tid  = threadIdx.x;
    const int lane = tid & 63;
    const int wave = tid >> 6;
    const int n    = lane & 15;   // vec-in-tile (B / D-col), cent (A-row)
    const int q    = lane >> 4;   // k-group; D-row group

    if (tid == 0) flg_n = 0;      // published by the first __syncthreads

    const int vbase = blockIdx.x * 128 + wave * 32;

    // B fragments: x_hi/x_lo, 2 K-blocks of 32, 2 tiles. 32 VGPRs.
    bf16x8 xhi[2][2], xlo[2][2];
#pragma unroll
    for (int t = 0; t < 2; ++t) {
        const float* vp = vecs + (size_t)(vbase + t * 16 + n) * DIM + q * 8;
#pragma unroll
        for (int kb = 0; kb < 2; ++kb) {
            float4 f0 = *(const float4*)(vp + kb * 32);
            float4 f1 = *(const float4*)(vp + kb * 32 + 4);
            float vv[8] = {f0.x, f0.y, f0.z, f0.w, f1.x, f1.y, f1.z, f1.w};
#pragma unroll
            for (int i = 0; i < 8; ++i) {
                unsigned short h = bf_rne(vv[i]);
                xhi[t][kb][i] = (short)h;
                xlo[t][kb][i] = (short)bf_rne(vv[i] - bf_up(h));
            }
        }
    }

    // stage group 0 (chunks 0,1 = 8 KB = 4 waves x 2 insts x 64 lanes x 16 B)
#pragma unroll
    for (int p = 0; p < 2; ++p) {
        int f  = wave * 2 + p;     // 0..7
        int cc = f >> 2;           // chunk within group
        int r  = f & 3;            // 1KB quarter
        const unsigned short* g = cmat + cc * 2048 + r * 512 + lane * 8;
        __builtin_amdgcn_global_load_lds(
            (const __attribute__((address_space(1))) void*)g,
            (__attribute__((address_space(3))) void*)(&chunkbuf[0][cc * 2048 + r * 512 + lane * 8]),
            16, 0, 0);
    }

    const unsigned UMAX = 0xFFFFFFFFu;
    unsigned min1[2] = {UMAX, UMAX};
    unsigned min2[2] = {UMAX, UMAX};

    for (int g = 0; g < NGRP; ++g) {
        __syncthreads();   // publishes buf[g&1]; drains in-flight staging
        if (g + 1 < NGRP) {
#pragma unroll
            for (int p = 0; p < 2; ++p) {
                int f  = wave * 2 + p;
                int cc = f >> 2;
                int r  = f & 3;
                const unsigned short* gp = cmat + ((g + 1) * 2 + cc) * 2048 + r * 512 + lane * 8;
                __builtin_amdgcn_global_load_lds(
                    (const __attribute__((address_space(1))) void*)gp,
                    (__attribute__((address_space(3))) void*)(&chunkbuf[(g + 1) & 1][cc * 2048 + r * 512 + lane * 8]),
                    16, 0, 0);
            }
        }
        const unsigned short* B = chunkbuf[g & 1];
#pragma unroll
        for (int cc2 = 0; cc2 < 2; ++cc2) {
            const int c = g * 2 + cc2;
            const unsigned short* Cb = B + cc2 * 2048 + lane * 8;
            bf16x8 a0 = *(const bf16x8*)(Cb);          // w_hi, k 0..31
            bf16x8 a1 = *(const bf16x8*)(Cb + 512);    // w_hi, k 32..63
            bf16x8 a2 = *(const bf16x8*)(Cb + 1024);   // w_lo, k 0..31
            bf16x8 a3 = *(const bf16x8*)(Cb + 1536);   // w_lo, k 32..63
            float4 cs = *(const float4*)(csq4k + c * 16 + q * 4);

            // C-init: acc = SCALE*csq + MAGIC -> final bits encode the score
            f32x4 acc[2];
            acc[0] = (f32x4){cs.x, cs.y, cs.z, cs.w};
            acc[1] = acc[0];
#pragma unroll
            for (int t = 0; t < 2; ++t) acc[t] = __builtin_amdgcn_mfma_f32_16x16x32_bf16(a0, xhi[t][0], acc[t], 0, 0, 0);
#pragma unroll
            for (int t = 0; t < 2; ++t) acc[t] = __builtin_amdgcn_mfma_f32_16x16x32_bf16(a1, xhi[t][1], acc[t], 0, 0, 0);
#pragma unroll
            for (int t = 0; t < 2; ++t) acc[t] = __builtin_amdgcn_mfma_f32_16x16x32_bf16(a2, xhi[t][0], acc[t], 0, 0, 0);
#pragma unroll
            for (int t = 0; t < 2; ++t) acc[t] = __builtin_amdgcn_mfma_f32_16x16x32_bf16(a3, xhi[t][1], acc[t], 0, 0, 0);
#pragma unroll
            for (int t = 0; t < 2; ++t) acc[t] = __builtin_amdgcn_mfma_f32_16x16x32_bf16(a0, xlo[t][0], acc[t], 0, 0, 0);
#pragma unroll
            for (int t = 0; t < 2; ++t) acc[t] = __builtin_amdgcn_mfma_f32_16x16x32_bf16(a1, xlo[t][1], acc[t], 0, 0, 0);

            const unsigned bg = (unsigned)(c * 16 + q * 4); // + r = centroid idx
#pragma unroll
            for (int t = 0; t < 2; ++t) {
#pragma unroll
                for (int r = 0; r < 4; ++r) {
                    // exponent+bit22 of acc are constant -> monotone unsigned
                    unsigned e = (__float_as_uint(acc[t][r]) << 10) + (bg + (unsigned)r);
                    min2[t] = min(min2[t], max(min1[t], e));   // old min1!
                    min1[t] = min(min1[t], e);
                }
            }
        }
    }

    // merge top-2 across the 4 quads of each vec-column
#pragma unroll
    for (int t = 0; t < 2; ++t) {
#pragma unroll
        for (int off = 16; off <= 32; off <<= 1) {
            unsigned o1 = (unsigned)__shfl_xor((int)min1[t], off, 64);
            unsigned o2 = (unsigned)__shfl_xor((int)min2[t], off, 64);
            unsigned nm2 = min(max(min1[t], o1), min(min2[t], o2));
            min1[t] = min(min1[t], o1);
            min2[t] = nm2;
        }
        if (lane < 16) {
            int slot = wave * 32 + t * 16 + lane;
            widx[slot] = (unsigned short)(min1[t] & 1023u);
            if ((min2[t] >> 10) - (min1[t] >> 10) < (unsigned)DELTA_INT) {
                int p = atomicAdd(&flg_n, 1);          // LDS atomic, block-local
                flg[p] = (unsigned short)slot;
            }
        }
    }

    __syncthreads();
    // fused gather: 128 rows x 64 floats, fully coalesced float4 stores
    const size_t obase = (size_t)blockIdx.x * 128;
#pragma unroll
    for (int gI = 0; gI < 8; ++gI) {
        int row = gI * 16 + (tid >> 4);
        int e = tid & 15;
        int idx = widx[row];
        ((float4*)out)[(obase + row) * 16 + e] =
            ((const float4*)cents)[(size_t)idx * 16 + e];
    }

    __syncthreads();   // gather stores drained -> rescue overwrites are ordered
    // fused exact rescue: one wave per flagged row (avg <1 row/block).
    // lane handles cents {j*64+lane}; exact fmaf chain identical to the old
    // rescue kernel; lexicographic (s, idx) wave argmin; overwrite the row.
    const int nf = flg_n;
    for (int i = wave; i < nf; i += 4) {
        const int slot = flg[i];
        const size_t vrow = obase + slot;
        const float4* xr = (const float4*)(vecs + vrow * DIM);
        float bs = 3.0e38f; int bi = 0;
        for (int j = 0; j < 16; ++j) {
            int cc = j * 64 + lane;            // ascending per lane
            const float4* cp2 = (const float4*)(cents + (size_t)cc * DIM);
            float a0 = 0.f, a1 = 0.f, a2 = 0.f, a3 = 0.f;
#pragma unroll
            for (int k = 0; k < DIM / 4; ++k) {
                float4 cv = cp2[k];
                float4 xv = xr[k];             // uniform addr, L1 broadcast
                a0 = fmaf(xv.x, cv.x, a0);
                a1 = fmaf(xv.y, cv.y, a1);
                a2 = fmaf(xv.z, cv.z, a2);
                a3 = fmaf(xv.w, cv.w, a3);
            }
            float d = (a0 + a1) + (a2 + a3);
            float s = fmaf(-2.f, d, csq[cc]);
            if (s < bs) { bs = s; bi = cc; }
        }
#pragma unroll
        for (int off = 1; off < 64; off <<= 1) {
            float os = __shfl_xor(bs, off, 64);
            int   oi = __shfl_xor(bi, off, 64);
            if (os < bs || (os == bs && oi < bi)) { bs = os; bi = oi; }
        }
        if (lane < 16)
            ((float4*)(out + vrow * DIM))[lane] =
                ((const float4*)(cents + (size_t)bi * DIM))[lane];
    }
}

extern "C" void kernel_launch(void* const* d_in, const int* in_sizes, int n_in,
                              void* d_out, int out_size, void* d_ws, size_t ws_size,
                              hipStream_t stream) {
    const float* vecs  = (const float*)d_in[0];
    const float* cents = (const float*)d_in[1];
    float*       out   = (float*)d_out;

    // ws layout (16B aligned)
    float*          csq     = (float*)d_ws;                                     //   4096 B
    float*          csq4k   = (float*)((char*)d_ws + 4096);                     //   4096 B
    unsigned short* cmat    = (unsigned short*)((char*)d_ws + 16384);           // 256 KB

    prep_kernel<<<dim3(64), dim3(256), 0, stream>>>(cents, csq, csq4k, cmat);
    assign_mfma<<<dim3(2048), dim3(256), 0, stream>>>(vecs, cents, cmat, csq4k, csq, out);
}

// Round 8
// 239.464 us; speedup vs baseline: 1.2459x; 1.2459x over previous
//
#include <hip/hip_runtime.h>
#include <hip/hip_bf16.h>

#define NVEC   262144
#define NLIST  1024
#define DIM    64
#define NCHUNK 64          // 64 chunks x 16 centroids
#define NGRP   32          // 2 chunks per barrier group
#define SCALE  4096.0f     // score quantum = 1/4096 (= acc ulp at 2^23)
#define MAGIC  10485760.0f // 2^23 + 2^21: pins acc exponent -> bits are monotone
#define DELTA_INT 48       // gap threshold in quanta >= 2x worst flag bound (~23q)

typedef __attribute__((ext_vector_type(8))) short bf16x8;
typedef __attribute__((ext_vector_type(4))) float f32x4;

__device__ __forceinline__ unsigned short bf_rne(float f) {
    unsigned int u = __float_as_uint(f);
    u += 0x7fffu + ((u >> 16) & 1u);
    return (unsigned short)(u >> 16);
}
__device__ __forceinline__ float bf_up(unsigned short s) {
    return __uint_as_float(((unsigned int)s) << 16);
}

// ---------------------------------------------------------------------------
// K0: csq (exact, for fused rescue) + csq4k = SCALE*csq + MAGIC (C-init),
// build cmat in FRAG ORDER with -2*SCALE = -8192 folded in:
//   w = -8192*c;  hi = bf_rne(w);  lo = bf_rne(w - hi)
// chunk ch = 4KB image [frag r 0..3][lane l][8 shorts]:
//   r=0: hi k 0..31   r=1: hi k 32..63   r=2: lo k 0..31   r=3: lo k 32..63
// assign's ds_read_b128 for frag r: lane l reads ch*4096+r*1024+l*16 —
// 64 lanes read a contiguous 1KB; staging order == global_load_lds order.
// ---------------------------------------------------------------------------
__global__ __launch_bounds__(256) void prep_kernel(const float* __restrict__ cents,
                                                   float* __restrict__ csq,
                                                   float* __restrict__ csq4k,
                                                   unsigned short* __restrict__ cmat) {
    int gid = blockIdx.x * 256 + threadIdx.x;     // 0..16383
    if (gid < NLIST) {
        const float4* p = (const float4*)(cents + (size_t)gid * DIM);
        float s = 0.f;
#pragma unroll
        for (int i = 0; i < DIM / 4; ++i) {
            float4 t = p[i];
            s += t.x * t.x + t.y * t.y + t.z * t.z + t.w * t.w;
        }
        csq[gid] = s;
        csq4k[gid] = fmaf(s, SCALE, MAGIC);
    }
    int c   = gid >> 4;        // centroid 0..1023
    int sub = gid & 15;        // r*4 + q
    int r   = sub >> 2;
    int qq  = sub & 3;
    const float* src = cents + (size_t)c * DIM + (r & 1) * 32 + qq * 8;
    unsigned short* dst = cmat + (c >> 4) * 2048 + r * 512 + (qq * 16 + (c & 15)) * 8;
    bool hi = (r < 2);
#pragma unroll
    for (int i = 0; i < 8; ++i) {
        float v = src[i] * -8192.0f;               // fold -2*SCALE, exact pow2
        unsigned short h = bf_rne(v);
        dst[i] = hi ? h : bf_rne(v - bf_up(h));
    }
}

// ---------------------------------------------------------------------------
// K1: MFMA assign + fused gather + FUSED exact rescue (2-kernel pipeline).
// Round-4 skeleton: LDS dbuf staging, grid 2048, 4 waves x 2 tiles/wave,
// (256,6) -> 6 blocks/CU.
// JOURNAL LESSONS:
//  r3/r5 — (256,8) forces VGPR<=32 -> spills. Budget at (256,6) is 84 VGPR.
//  r6/r7 — a register-HEAVY fused tail (fully-unrolled float4 k-loop, ~128
//  regs demanded) makes the allocator spill (+18 MB WRITE, one-time/thread)
//  and stretches the MAIN loop 1.9x (busy counts unchanged). The tail must
//  be register-trivial: x staged in (dead) chunkbuf LDS, unroll capped at 4.
// Numerics:
//   cmat = -8192*c split hi/lo (bf16 3-term); x split hi/lo (unscaled)
//   acc init = SCALE*csq + MAGIC; acc += w_hi.x_hi + w_lo.x_hi + w_hi.x_lo
//   final acc in [2^23, 2^24): exponent + mantissa bit22 constant -> raw
//   float bits are a monotone unsigned encoding of the quantized score.
// Epilogue per score (4 VALU): e = (bits<<10)+idx; top-2 via min/max/min.
// Flags (gap < DELTA quanta) are BLOCK-LOCAL -> collected in LDS; after the
// gather each wave exact-fp32-rescues one flagged row (same fmaf chain +
// lexicographic argmin as the verified rescue kernel) and overwrites the row.
// ---------------------------------------------------------------------------
__global__ __launch_bounds__(256, 6) void assign_mfma(const float* __restrict__ vecs,
                                                      const float* __restrict__ cents,
                                                      const unsigned short* __restrict__ cmat,
                                                      const float* __restrict__ csq4k,
                                                      const float* __restrict__ csq,
                                                      float* __restrict__ out) {
    __shared__ __align__(16) unsigned short chunkbuf[2][2 * 2048];  // 16 KB
    __shared__ unsigned short widx[128];                            // 256 B
    __shared__ unsigned short flg[128];
    __shared__ int flg_n;

    const int tid  = threadIdx.x;
    const int lane = tid & 63;
    const int wave = tid >> 6;
    const int n    = lane & 15;   // vec-in-tile (B / D-col), cent (A-row)
    const int q    = lane >> 4;   // k-group; D-row group

    if (tid == 0) flg_n = 0;      // published by the first __syncthreads

    const int vbase = blockIdx.x * 128 + wave * 32;

    // B fragments: x_hi/x_lo, 2 K-blocks of 32, 2 tiles. 32 VGPRs.
    bf16x8 xhi[2][2], xlo[2][2];
#pragma unroll
    for (int t = 0; t < 2; ++t) {
        const float* vp = vecs + (size_t)(vbase + t * 16 + n) * DIM + q * 8;
#pragma unroll
        for (int kb = 0; kb < 2; ++kb) {
            float4 f0 = *(const float4*)(vp + kb * 32);
            float4 f1 = *(const float4*)(vp + kb * 32 + 4);
            float vv[8] = {f0.x, f0.y, f0.z, f0.w, f1.x, f1.y, f1.z, f1.w};
#pragma unroll
            for (int i = 0; i < 8; ++i) {
                unsigned short h = bf_rne(vv[i]);
                xhi[t][kb][i] = (short)h;
                xlo[t][kb][i] = (short)bf_rne(vv[i] - bf_up(h));
            }
        }
    }

    // stage group 0 (chunks 0,1 = 8 KB = 4 waves x 2 insts x 64 lanes x 16 B)
#pragma unroll
    for (int p = 0; p < 2; ++p) {
        int f  = wave * 2 + p;     // 0..7
        int cc = f >> 2;           // chunk within group
        int r  = f & 3;            // 1KB quarter
        const unsigned short* g = cmat + cc * 2048 + r * 512 + lane * 8;
        __builtin_amdgcn_global_load_lds(
            (const __attribute__((address_space(1))) void*)g,
            (__attribute__((address_space(3))) void*)(&chunkbuf[0][cc * 2048 + r * 512 + lane * 8]),
            16, 0, 0);
    }

    const unsigned UMAX = 0xFFFFFFFFu;
    unsigned min1[2] = {UMAX, UMAX};
    unsigned min2[2] = {UMAX, UMAX};

    for (int g = 0; g < NGRP; ++g) {
        __syncthreads();   // publishes buf[g&1]; drains in-flight staging
        if (g + 1 < NGRP) {
#pragma unroll
            for (int p = 0; p < 2; ++p) {
                int f  = wave * 2 + p;
                int cc = f >> 2;
                int r  = f & 3;
                const unsigned short* gp = cmat + ((g + 1) * 2 + cc) * 2048 + r * 512 + lane * 8;
                __builtin_amdgcn_global_load_lds(
                    (const __attribute__((address_space(1))) void*)gp,
                    (__attribute__((address_space(3))) void*)(&chunkbuf[(g + 1) & 1][cc * 2048 + r * 512 + lane * 8]),
                    16, 0, 0);
            }
        }
        const unsigned short* B = chunkbuf[g & 1];
#pragma unroll
        for (int cc2 = 0; cc2 < 2; ++cc2) {
            const int c = g * 2 + cc2;
            const unsigned short* Cb = B + cc2 * 2048 + lane * 8;
            bf16x8 a0 = *(const bf16x8*)(Cb);          // w_hi, k 0..31
            bf16x8 a1 = *(const bf16x8*)(Cb + 512);    // w_hi, k 32..63
            bf16x8 a2 = *(const bf16x8*)(Cb + 1024);   // w_lo, k 0..31
            bf16x8 a3 = *(const bf16x8*)(Cb + 1536);   // w_lo, k 32..63
            float4 cs = *(const float4*)(csq4k + c * 16 + q * 4);

            // C-init: acc = SCALE*csq + MAGIC -> final bits encode the score
            f32x4 acc[2];
            acc[0] = (f32x4){cs.x, cs.y, cs.z, cs.w};
            acc[1] = acc[0];
#pragma unroll
            for (int t = 0; t < 2; ++t) acc[t] = __builtin_amdgcn_mfma_f32_16x16x32_bf16(a0, xhi[t][0], acc[t], 0, 0, 0);
#pragma unroll
            for (int t = 0; t < 2; ++t) acc[t] = __builtin_amdgcn_mfma_f32_16x16x32_bf16(a1, xhi[t][1], acc[t], 0, 0, 0);
#pragma unroll
            for (int t = 0; t < 2; ++t) acc[t] = __builtin_amdgcn_mfma_f32_16x16x32_bf16(a2, xhi[t][0], acc[t], 0, 0, 0);
#pragma unroll
            for (int t = 0; t < 2; ++t) acc[t] = __builtin_amdgcn_mfma_f32_16x16x32_bf16(a3, xhi[t][1], acc[t], 0, 0, 0);
#pragma unroll
            for (int t = 0; t < 2; ++t) acc[t] = __builtin_amdgcn_mfma_f32_16x16x32_bf16(a0, xlo[t][0], acc[t], 0, 0, 0);
#pragma unroll
            for (int t = 0; t < 2; ++t) acc[t] = __builtin_amdgcn_mfma_f32_16x16x32_bf16(a1, xlo[t][1], acc[t], 0, 0, 0);

            const unsigned bg = (unsigned)(c * 16 + q * 4); // + r = centroid idx
#pragma unroll
            for (int t = 0; t < 2; ++t) {
#pragma unroll
                for (int r = 0; r < 4; ++r) {
                    // exponent+bit22 of acc are constant -> monotone unsigned
                    unsigned e = (__float_as_uint(acc[t][r]) << 10) + (bg + (unsigned)r);
                    min2[t] = min(min2[t], max(min1[t], e));   // old min1!
                    min1[t] = min(min1[t], e);
                }
            }
        }
    }

    // merge top-2 across the 4 quads of each vec-column
#pragma unroll
    for (int t = 0; t < 2; ++t) {
#pragma unroll
        for (int off = 16; off <= 32; off <<= 1) {
            unsigned o1 = (unsigned)__shfl_xor((int)min1[t], off, 64);
            unsigned o2 = (unsigned)__shfl_xor((int)min2[t], off, 64);
            unsigned nm2 = min(max(min1[t], o1), min(min2[t], o2));
            min1[t] = min(min1[t], o1);
            min2[t] = nm2;
        }
        if (lane < 16) {
            int slot = wave * 32 + t * 16 + lane;
            widx[slot] = (unsigned short)(min1[t] & 1023u);
            if ((min2[t] >> 10) - (min1[t] >> 10) < (unsigned)DELTA_INT) {
                int p = atomicAdd(&flg_n, 1);          // LDS atomic, block-local
                flg[p] = (unsigned short)slot;
            }
        }
    }

    __syncthreads();
    // fused gather: 128 rows x 64 floats, fully coalesced float4 stores
    const size_t obase = (size_t)blockIdx.x * 128;
#pragma unroll
    for (int gI = 0; gI < 8; ++gI) {
        int row = gI * 16 + (tid >> 4);
        int e = tid & 15;
        int idx = widx[row];
        ((float4*)out)[(obase + row) * 16 + e] =
            ((const float4*)cents)[(size_t)idx * 16 + e];
    }

    __syncthreads();   // gather stores drained -> rescue overwrites are ordered
    // fused exact rescue: one wave per flagged row (avg <1 row/block).
    // REGISTER-TRIVIAL (r6/r7 lesson): x staged into dead chunkbuf LDS
    // (256 B per wave slice), k-loop unroll capped at 4 -> peak ~35 VGPRs.
    // Exact fmaf chain + lexicographic (s, idx) argmin == verified rescue.
    const int nf = flg_n;
    float* xls = ((float*)chunkbuf) + wave * DIM;   // chunkbuf dead after loop
    for (int i = wave; i < nf; i += 4) {
        const int slot = flg[i];
        const size_t vrow = obase + slot;
        if (lane < 16)
            ((float4*)xls)[lane] = ((const float4*)(vecs + vrow * DIM))[lane];
        // same-wave LDS write->read; compiler inserts the lgkmcnt wait
        float bs = 3.0e38f; int bi = 0;
        for (int j = 0; j < 16; ++j) {
            int cc = j * 64 + lane;            // ascending per lane
            const float4* cp2 = (const float4*)(cents + (size_t)cc * DIM);
            float a0 = 0.f, a1 = 0.f, a2 = 0.f, a3 = 0.f;
#pragma unroll 4
            for (int k = 0; k < DIM / 4; ++k) {
                float4 cv = cp2[k];
                float4 xv = ((const float4*)xls)[k];
                a0 = fmaf(xv.x, cv.x, a0);
                a1 = fmaf(xv.y, cv.y, a1);
                a2 = fmaf(xv.z, cv.z, a2);
                a3 = fmaf(xv.w, cv.w, a3);
            }
            float d = (a0 + a1) + (a2 + a3);
            float s = fmaf(-2.f, d, csq[cc]);
            if (s < bs) { bs = s; bi = cc; }
        }
#pragma unroll
        for (int off = 1; off < 64; off <<= 1) {
            float os = __shfl_xor(bs, off, 64);
            int   oi = __shfl_xor(bi, off, 64);
            if (os < bs || (os == bs && oi < bi)) { bs = os; bi = oi; }
        }
        if (lane < 16)
            ((float4*)(out + vrow * DIM))[lane] =
                ((const float4*)(cents + (size_t)bi * DIM))[lane];
    }
}

extern "C" void kernel_launch(void* const* d_in, const int* in_sizes, int n_in,
                              void* d_out, int out_size, void* d_ws, size_t ws_size,
                              hipStream_t stream) {
    const float* vecs  = (const float*)d_in[0];
    const float* cents = (const float*)d_in[1];
    float*       out   = (float*)d_out;

    // ws layout (16B aligned)
    float*          csq     = (float*)d_ws;                                     //   4096 B
    float*          csq4k   = (float*)((char*)d_ws + 4096);                     //   4096 B
    unsigned short* cmat    = (unsigned short*)((char*)d_ws + 16384);           // 256 KB

    prep_kernel<<<dim3(64), dim3(256), 0, stream>>>(cents, csq, csq4k, cmat);
    assign_mfma<<<dim3(2048), dim3(256), 0, stream>>>(vecs, cents, cmat, csq4k, csq, out);
}